// Round 1
// baseline (616.426 us; speedup 1.0000x reference)
//
#include <hip/hip_runtime.h>

// k-th NN distance (k=32 -> 33rd smallest incl. ties, self excluded) for
// B=16384 points, D=128, fp32 in/out.
//
// Pipeline: prep (bf16 + norm-augmented operands) -> closed-form per-row
// threshold -> MFMA gram with fused filter/collect -> per-row exact select
// of 33rd smallest among collected candidates -> brute-force fallback for
// any row whose candidate set is invalid (guarantees exactness).

typedef unsigned short u16;
typedef unsigned int   u32;
typedef __attribute__((ext_vector_type(8))) u16    ushort8;
typedef __attribute__((ext_vector_type(8))) __bf16 bf16x8;
typedef __attribute__((ext_vector_type(4))) float  f32x4;

#define NB   16384
#define ND   128
#define KP   160          // padded K: 0..127 data, 128..129 norm-fold, 130..159 zero
#define CAP  384          // candidate slots per row
#define NTH  33           // 33rd smallest
#define LAMBDA 2.15f
#define NEGF (-3.0e38f)
#define POSF ( 3.0e38f)

// ---- workspace layout (bytes) ----
#define OFF_XA   ((size_t)0)
#define OFF_XB   (OFF_XA + (size_t)NB * KP * 2)
#define OFF_NORM (OFF_XB + (size_t)NB * KP * 2)
#define OFF_TACC (OFF_NORM + (size_t)NB * 4)
#define OFF_XBAR (OFF_TACC + (size_t)NB * 4)
#define OFF_SCAL (OFF_XBAR + 512)
#define OFF_CNT  (OFF_SCAL + 256)
#define OFF_CAND (OFF_CNT + (size_t)NB * 4)

static __device__ __forceinline__ u16 f2bf(float f) {
  u32 u = __float_as_uint(f);
  u32 r = u + 0x7FFFu + ((u >> 16) & 1u);
  return (u16)(r >> 16);
}
static __device__ __forceinline__ float bf2f(u16 h) {
  return __uint_as_float(((u32)h) << 16);
}

// ---------------- K1z: zero counters / accumulators (every launch) --------
__global__ void k_zero(int* cnt, float* xbar, float* scal) {
  int i = blockIdx.x * 256 + threadIdx.x;
  if (i < NB)  cnt[i] = 0;
  if (i < 128) xbar[i] = 0.f;
  if (i < 2)   scal[i] = 0.f;
}

// ---------------- K1a: bf16 convert + norms + augmented operand rows ------
// Xa row (A-operand / streamed cols): [x(128), -n/2 hi, -n/2 lo, 0...]
// Xb row (B-operand / owned rows)   : [x(128),  1,      1,      0...]
// => mfma acc = x_c . x_r - n_c/2 ; sq = n_r - 2*acc
__global__ void k_prep(const float* __restrict__ x, u16* __restrict__ Xa,
                       u16* __restrict__ Xb, float* __restrict__ norms) {
  int w = threadIdx.x >> 6, l = threadIdx.x & 63;
  int r = blockIdx.x * 4 + w;  // grid 4096, one wave per row
  const float2* xr2 = (const float2*)(x + (size_t)r * ND);
  float2 a = xr2[l];
  u16 h0 = f2bf(a.x), h1 = f2bf(a.y);
  float b0 = bf2f(h0), b1 = bf2f(h1);
  float n = b0 * b0 + b1 * b1;
#pragma unroll
  for (int off = 1; off < 64; off <<= 1) n += __shfl_xor(n, off, 64);
  u16* xar = Xa + (size_t)r * KP;
  u16* xbr = Xb + (size_t)r * KP;
  xar[2 * l] = h0; xar[2 * l + 1] = h1;
  xbr[2 * l] = h0; xbr[2 * l + 1] = h1;
  if (l == 0) {
    float nh = -0.5f * n;
    u16 hh = f2bf(nh);
    u16 hl = f2bf(nh - bf2f(hh));
    xar[128] = hh;     xar[129] = hl;
    xbr[128] = 0x3F80; xbr[129] = 0x3F80;  // 1.0bf16, 1.0bf16
    for (int kk = 130; kk < KP; ++kk) { xar[kk] = 0; xbr[kk] = 0; }
    norms[r] = n;
  }
}

// ---------------- K1b: column sums (x-bar) + sum(n), sum(n^2) -------------
__global__ void k_stats(const u16* __restrict__ Xb, const float* __restrict__ norms,
                        float* xbar, float* scal) {
  __shared__ float xs[2][128];
  __shared__ float red1[256], red2[256];
  int t = threadIdx.x, col = t & 127, half = t >> 7;
  int rbase = blockIdx.x * 256 + half * 128;  // grid 64
  float acc = 0.f;
  for (int rr = 0; rr < 128; ++rr)
    acc += bf2f(Xb[(size_t)(rbase + rr) * KP + col]);
  xs[half][col] = acc;
  float ln = norms[blockIdx.x * 256 + t];
  red1[t] = ln; red2[t] = ln * ln;
  __syncthreads();
  for (int s = 128; s > 0; s >>= 1) {
    if (t < s) { red1[t] += red1[t + s]; red2[t] += red2[t + s]; }
    __syncthreads();
  }
  if (t == 0) { atomicAdd(&scal[0], red1[0]); atomicAdd(&scal[1], red2[0]); }
  if (t < 128) atomicAdd(&xbar[t], xs[0][t] + xs[1][t]);
}

// ---------------- K1c: per-row threshold (acc-space) ----------------------
__global__ void k_thresh(const u16* __restrict__ Xb, const float* __restrict__ norms,
                         const float* __restrict__ xbar, const float* __restrict__ scal,
                         float* __restrict__ tacc) {
  __shared__ float xb[128];
  int t = threadIdx.x;
  if (t < 128) xb[t] = xbar[t] * (1.0f / NB);
  __syncthreads();
  int r = blockIdx.x * 256 + t;  // grid 64
  float n = norms[r];
  const u16* xr = Xb + (size_t)r * KP;
  float dot = 0.f;
#pragma unroll
  for (int c8 = 0; c8 < 16; ++c8) {
    ushort8 v = *(const ushort8*)(xr + c8 * 8);
#pragma unroll
    for (int j = 0; j < 8; ++j) dot += bf2f(v[j]) * xb[c8 * 8 + j];
  }
  float nbar = scal[0] * (1.0f / NB);
  float Vn = fmaxf(scal[1] * (1.0f / NB) - nbar * nbar, 0.f);
  float mu = n + nbar - 2.f * dot;                    // exact E_j[sq_rj]
  float sig = sqrtf(Vn + 4.f * n * (nbar / ND));      // model; errors caught by cnt check
  float tsq = mu - LAMBDA * sig;
  tacc[r] = 0.5f * (n - tsq);   // sq <= tsq  <=>  acc >= tacc
}

// ---------------- K2: MFMA gram + fused filter/collect --------------------
// grid 512 = 128 row-strips x 4 col-quarters; 256 thr = 4 waves (2x2 of 64x64)
// LDS layout: fragment groups g=(k*8+m16), each 64 lanes x 16B contiguous.
__global__ __launch_bounds__(256) void k_gram(
    const u16* __restrict__ Xa, const u16* __restrict__ Xb,
    const float* __restrict__ tacc, int* __restrict__ cnt,
    float* __restrict__ cands) {
  __shared__ u16 ldsA[40 * 512];
  __shared__ u16 ldsB[40 * 512];
  int bid = blockIdx.x;
  int strip = bid >> 2, q = bid & 3;
  int r0 = strip * 128;
  int t = threadIdx.x, w = t >> 6, l = t & 63;
  int wr = w & 1, wc = w >> 1;
  int lm = l & 15, lq = l >> 4;

  // stage B tile (owned rows) once
  {
    const u16* src = Xb + (size_t)r0 * KP;
#pragma unroll
    for (int s = 0; s < 10; ++s) {
      int g = w * 10 + s; int k = g >> 3, m16 = g & 7;
      ushort8 v = *(const ushort8*)(src + (size_t)(m16 * 16 + lm) * KP + k * 32 + lq * 8);
      *(ushort8*)(&ldsB[g * 512 + l * 8]) = v;
    }
  }
  int rj[4]; float tj[4];
#pragma unroll
  for (int j = 0; j < 4; ++j) {
    rj[j] = r0 + (wr * 4 + j) * 16 + lm;
    tj[j] = tacc[rj[j]];
  }
  __syncthreads();

  for (int it = 0; it < 32; ++it) {
    int c0 = q * 4096 + it * 128;
    // load next A tile to regs (overlaps prior compute tail)
    ushort8 stg[10];
    const u16* srcA = Xa + (size_t)c0 * KP;
#pragma unroll
    for (int s = 0; s < 10; ++s) {
      int g = w * 10 + s; int k = g >> 3, m16 = g & 7;
      stg[s] = *(const ushort8*)(srcA + (size_t)(m16 * 16 + lm) * KP + k * 32 + lq * 8);
    }
    __syncthreads();  // everyone done reading ldsA from prev iter
#pragma unroll
    for (int s = 0; s < 10; ++s) {
      int g = w * 10 + s;
      *(ushort8*)(&ldsA[g * 512 + l * 8]) = stg[s];
    }
    __syncthreads();

    f32x4 acc[4][4];
#pragma unroll
    for (int i = 0; i < 4; ++i)
#pragma unroll
      for (int j = 0; j < 4; ++j) acc[i][j] = (f32x4){0.f, 0.f, 0.f, 0.f};

#pragma unroll
    for (int k = 0; k < 5; ++k) {
      bf16x8 af[4], bfv[4];
#pragma unroll
      for (int i = 0; i < 4; ++i)
        af[i] = __builtin_bit_cast(bf16x8,
                 *(const ushort8*)(&ldsA[(k * 8 + wc * 4 + i) * 512 + l * 8]));
#pragma unroll
      for (int j = 0; j < 4; ++j)
        bfv[j] = __builtin_bit_cast(bf16x8,
                 *(const ushort8*)(&ldsB[(k * 8 + wr * 4 + j) * 512 + l * 8]));
#pragma unroll
      for (int i = 0; i < 4; ++i)
#pragma unroll
        for (int j = 0; j < 4; ++j)
          acc[i][j] = __builtin_amdgcn_mfma_f32_16x16x32_bf16(af[i], bfv[j], acc[i][j], 0, 0, 0);
    }

    // filter + collect (acc >= tacc  <=>  sq <= tsq); bigger acc = closer
    bool diag = (c0 == r0);
#pragma unroll
    for (int i = 0; i < 4; ++i) {
      int cb = c0 + (wc * 4 + i) * 16 + lq * 4;
#pragma unroll
      for (int j = 0; j < 4; ++j) {
#pragma unroll
        for (int v = 0; v < 4; ++v) {
          float val = acc[i][j][v];
          bool p = (val >= tj[j]);
          if (diag) p = p && ((cb + v) != rj[j]);
          if (p) {
            int pos = atomicAdd(&cnt[rj[j]], 1);
            if (pos < CAP) cands[(size_t)rj[j] * CAP + pos] = val;
          }
        }
      }
    }
  }
}

// ---------------- K3: per-row exact 33rd smallest among candidates --------
__global__ void k_select(const int* __restrict__ cnt, const float* __restrict__ cands,
                         const float* __restrict__ norms, float* __restrict__ out) {
  int w = threadIdx.x >> 6, l = threadIdx.x & 63;
  int r = blockIdx.x * 4 + w;  // grid 4096
  int c = cnt[r];
  if (c < NTH || c > CAP) return;  // fallback kernel owns this row
  size_t base = (size_t)r * CAP;
  float v0 = (l       < c) ? cands[base + l      ] : NEGF;
  float v1 = (l +  64 < c) ? cands[base + l +  64] : NEGF;
  float v2 = (l + 128 < c) ? cands[base + l + 128] : NEGF;
  float v3 = (l + 192 < c) ? cands[base + l + 192] : NEGF;
  float v4 = (l + 256 < c) ? cands[base + l + 256] : NEGF;
  float v5 = (l + 320 < c) ? cands[base + l + 320] : NEGF;
  float last = NEGF;
  for (int e = 0; e < NTH; ++e) {
    float m = fmaxf(fmaxf(fmaxf(v0, v1), fmaxf(v2, v3)), fmaxf(v4, v5));
#pragma unroll
    for (int off = 1; off < 64; off <<= 1) m = fmaxf(m, __shfl_xor(m, off, 64));
    bool mine = (v0 == m) || (v1 == m) || (v2 == m) || (v3 == m) || (v4 == m) || (v5 == m);
    unsigned long long bal = __ballot(mine);
    int owner = __ffsll(bal) - 1;
    if (l == owner) {  // remove exactly one instance
      if      (v0 == m) v0 = NEGF;
      else if (v1 == m) v1 = NEGF;
      else if (v2 == m) v2 = NEGF;
      else if (v3 == m) v3 = NEGF;
      else if (v4 == m) v4 = NEGF;
      else              v5 = NEGF;
    }
    last = m;
  }
  out[r] = sqrtf(fmaxf(norms[r] - 2.f * last, 0.f));  // sq = n_r - 2*acc
}

// ---------------- K4: exact brute-force fallback (expected 0 rows) --------
__global__ void k_fallback(const int* __restrict__ cnt, const u16* __restrict__ Xb,
                           const float* __restrict__ norms, float* __restrict__ out) {
  __shared__ float sq[NB];     // 64 KB
  __shared__ float xr[ND];
  __shared__ float rmin[256];
  __shared__ int   ridx[256];
  int t = threadIdx.x;
  for (int r = blockIdx.x; r < NB; r += 64) {  // grid 64
    int c = cnt[r];
    if (c >= NTH && c <= CAP) continue;  // uniform branch, safe w/ barriers below
    if (t < 128) xr[t] = bf2f(Xb[(size_t)r * KP + t]);
    __syncthreads();
    float n_r = norms[r];
    for (int jj = 0; jj < 64; ++jj) {
      int j = t + 256 * jj;
      const u16* xj = Xb + (size_t)j * KP;
      float dot = 0.f;
      for (int d = 0; d < ND; ++d) dot += bf2f(xj[d]) * xr[d];
      sq[j] = (j == r) ? POSF : fmaxf(n_r + norms[j] - 2.f * dot, 0.f);
    }
    __syncthreads();
    float last = 0.f;
    for (int e = 0; e < NTH; ++e) {
      float lm = POSF; int li = -1;
      for (int jj = 0; jj < 64; ++jj) {
        int j = t + 256 * jj;
        float s = sq[j];
        if (s < lm) { lm = s; li = j; }
      }
      rmin[t] = lm; ridx[t] = li;
      __syncthreads();
      if (t == 0) {
        float gm = POSF; int gi = -1;
        for (int u = 0; u < 256; ++u)
          if (rmin[u] < gm) { gm = rmin[u]; gi = ridx[u]; }
        sq[gi] = POSF;
        rmin[0] = gm;
      }
      __syncthreads();
      last = rmin[0];
      __syncthreads();
    }
    if (t == 0) out[r] = sqrtf(fmaxf(last, 0.f));
    __syncthreads();
  }
}

extern "C" void kernel_launch(void* const* d_in, const int* in_sizes, int n_in,
                              void* d_out, int out_size, void* d_ws, size_t ws_size,
                              hipStream_t stream) {
  const float* x = (const float*)d_in[0];
  float* out = (float*)d_out;
  char* ws = (char*)d_ws;
  u16*   Xa    = (u16*)  (ws + OFF_XA);
  u16*   Xb    = (u16*)  (ws + OFF_XB);
  float* norms = (float*)(ws + OFF_NORM);
  float* tacc  = (float*)(ws + OFF_TACC);
  float* xbar  = (float*)(ws + OFF_XBAR);
  float* scal  = (float*)(ws + OFF_SCAL);
  int*   cnt   = (int*)  (ws + OFF_CNT);
  float* cands = (float*)(ws + OFF_CAND);

  k_zero    <<<64,   256, 0, stream>>>(cnt, xbar, scal);
  k_prep    <<<4096, 256, 0, stream>>>(x, Xa, Xb, norms);
  k_stats   <<<64,   256, 0, stream>>>(Xb, norms, xbar, scal);
  k_thresh  <<<64,   256, 0, stream>>>(Xb, norms, xbar, scal, tacc);
  k_gram    <<<512,  256, 0, stream>>>(Xa, Xb, tacc, cnt, cands);
  k_select  <<<4096, 256, 0, stream>>>(cnt, cands, norms, out);
  k_fallback<<<64,   256, 0, stream>>>(cnt, Xb, norms, out);
}

// Round 3
// 316.198 us; speedup vs baseline: 1.9495x; 1.9495x over previous
//
#include <hip/hip_runtime.h>

// k-th NN distance (k=32 -> 33rd smallest, self excluded), B=16384, D=128.
// R2 resubmit (container infra failure, no signal): no atomics (segmented
// per-lane candidate buffers), per-row Wilson-Hilferty chi^2 threshold
// (z=-2.62, ~72 cands/row), KP=128 with exact fp32 column-norm correction
// in the filter epilogue, global_load_lds staging. Exactness guaranteed by
// per-segment count checks + brute-force fallback.

typedef unsigned short u16;
typedef unsigned int   u32;
typedef __attribute__((ext_vector_type(8))) u16    ushort8;
typedef __attribute__((ext_vector_type(8))) __bf16 bf16x8;
typedef __attribute__((ext_vector_type(4))) float  f32x4;

#define NB   16384
#define ND   128
#define NSEG 32           // segments per row = 4 q * 2 wc * 4 lq
#define SCAP 12           // slots per segment (mean ~2.25, 12 = ~6 sigma)
#define NTH  33           // 33rd smallest
#define ZWH  (-2.62f)     // WH quantile z: p~0.0044 -> ~72 cands/row
#define NEGF (-3.0e38f)
#define POSF ( 3.0e38f)

// ---- workspace layout (bytes), total ~31.6 MB ----
#define OFF_X    ((size_t)0)
#define OFF_NORM (OFF_X    + (size_t)NB * ND * 2)
#define OFF_TACC (OFF_NORM + (size_t)NB * 4)
#define OFF_XBAR (OFF_TACC + (size_t)NB * 4)
#define OFF_SCAL (OFF_XBAR + 512)
#define OFF_CNTS (OFF_SCAL + 256)
#define OFF_CAND (OFF_CNTS + (size_t)NB * NSEG * 4)

static __device__ __forceinline__ u16 f2bf(float f) {
  u32 u = __float_as_uint(f);
  u32 r = u + 0x7FFFu + ((u >> 16) & 1u);
  return (u16)(r >> 16);
}
static __device__ __forceinline__ float bf2f(u16 h) {
  return __uint_as_float(((u32)h) << 16);
}

#if defined(__has_builtin)
#if __has_builtin(__builtin_amdgcn_global_load_lds)
#define HAVE_GLDS 1
#endif
#endif

// Stage one fragment group: 64 lanes x 16B, LDS dest linear in lane.
static __device__ __forceinline__ void stage_group(const u16* gsrc_lane,
                                                   u16* lds_base, int l) {
#ifdef HAVE_GLDS
  __builtin_amdgcn_global_load_lds(
      (const __attribute__((address_space(1))) void*)gsrc_lane,
      (__attribute__((address_space(3))) void*)lds_base, 16, 0, 0);
#else
  *(ushort8*)(lds_base + l * 8) = *(const ushort8*)gsrc_lane;
#endif
}

// ---------------- K1: bf16 convert + norms (+ zero stat accumulators) ----
__global__ void k_prep(const float* __restrict__ x, u16* __restrict__ X,
                       float* __restrict__ norms, float* xbar, float* scal) {
  if (blockIdx.x == 0) {
    int tt = threadIdx.x;
    if (tt < 128) xbar[tt] = 0.f;
    if (tt < 2)   scal[tt] = 0.f;
  }
  int w = threadIdx.x >> 6, l = threadIdx.x & 63;
  int r = blockIdx.x * 4 + w;  // grid 4096
  const float2* xr2 = (const float2*)(x + (size_t)r * ND);
  float2 a = xr2[l];
  u16 h0 = f2bf(a.x), h1 = f2bf(a.y);
  float b0 = bf2f(h0), b1 = bf2f(h1);
  float n = b0 * b0 + b1 * b1;
#pragma unroll
  for (int off = 1; off < 64; off <<= 1) n += __shfl_xor(n, off, 64);
  *(u32*)(X + (size_t)r * ND + 2 * l) = (u32)h0 | ((u32)h1 << 16);
  if (l == 0) norms[r] = n;
}

// ---------------- K2: column sums (x-bar) + sum(n), sum(n^2) -------------
__global__ void k_stats(const u16* __restrict__ X, const float* __restrict__ norms,
                        float* xbar, float* scal) {
  __shared__ float xs[2][128];
  __shared__ float red1[256], red2[256];
  int t = threadIdx.x, col = t & 127, half = t >> 7;
  int rbase = blockIdx.x * 256 + half * 128;  // grid 64
  float acc = 0.f;
  for (int rr = 0; rr < 128; ++rr)
    acc += bf2f(X[(size_t)(rbase + rr) * ND + col]);
  xs[half][col] = acc;
  float ln = norms[blockIdx.x * 256 + t];
  red1[t] = ln; red2[t] = ln * ln;
  __syncthreads();
  for (int s = 128; s > 0; s >>= 1) {
    if (t < s) { red1[t] += red1[t + s]; red2[t] += red2[t + s]; }
    __syncthreads();
  }
  if (t == 0) { atomicAdd(&scal[0], red1[0]); atomicAdd(&scal[1], red2[0]); }
  if (t < 128) atomicAdd(&xbar[t], xs[0][t] + xs[1][t]);
}

// ---------------- K3: per-row threshold via Wilson-Hilferty chi^2 --------
__global__ void k_thresh(const u16* __restrict__ X, const float* __restrict__ norms,
                         const float* __restrict__ xbar, const float* __restrict__ scal,
                         float* __restrict__ tacc) {
  __shared__ float xb[128];
  int t = threadIdx.x;
  if (t < 128) xb[t] = xbar[t] * (1.0f / NB);
  __syncthreads();
  int r = blockIdx.x * 256 + t;  // grid 64
  float n = norms[r];
  const u16* xr = X + (size_t)r * ND;
  float dot = 0.f;
#pragma unroll
  for (int c8 = 0; c8 < 16; ++c8) {
    ushort8 v = *(const ushort8*)(xr + c8 * 8);
#pragma unroll
    for (int j = 0; j < 8; ++j) dot += bf2f(v[j]) * xb[c8 * 8 + j];
  }
  float nbar = scal[0] * (1.0f / NB);
  float Vn = fmaxf(scal[1] * (1.0f / NB) - nbar * nbar, 0.f);
  float m = n + nbar - 2.f * dot;             // exact E_j[sq_rj]
  float v = Vn + 4.f * n * (nbar / ND);       // exact Var_j[sq_rj] (Gaussian)
  // match mean/var to c*chi2(nu), take WH lower quantile at z=ZWH
  float nu = 2.f * m * m / v;
  float cc = v / (2.f * m);
  float a1 = 2.f / (9.f * nu);
  float inner = 1.f - a1 + ZWH * sqrtf(a1);
  float tsq = cc * nu * inner * inner * inner;
  tacc[r] = 0.5f * (n - tsq);   // val = acc - nc/2 >= tacc  <=>  sq <= tsq
}

// ---------------- K4: MFMA gram + fused filter into private segments -----
// grid 512 = 128 row-strips x 4 col-quarters; 4 waves as 2x2 of 64x64.
// Candidate segment (row, q, wc, lq): per-lane register counter, no atomics.
__global__ __launch_bounds__(256) void k_gram(
    const u16* __restrict__ X, const float* __restrict__ norms,
    const float* __restrict__ tacc, u32* __restrict__ counts,
    float* __restrict__ cands) {
  __shared__ u16 ldsA[32 * 512];
  __shared__ u16 ldsB[32 * 512];
  __shared__ __align__(16) float nchs[128];
  const int bid = blockIdx.x;
  const int strip = bid >> 2, q = bid & 3;
  const int r0 = strip * 128;
  const int t = threadIdx.x, w = t >> 6, l = t & 63;
  const int wr = w & 1, wc = w >> 1;
  const int lm = l & 15, lq = l >> 4;
  const int koff = lq * 8;

  // stage B tile (owned rows) once: group g -> k=g>>3, entity16=g&7
#pragma unroll
  for (int s = 0; s < 8; ++s) {
    int g = w * 8 + s;
    stage_group(X + (size_t)(r0 + (g & 7) * 16 + lm) * ND + (g >> 3) * 32 + koff,
                &ldsB[g * 512], l);
  }
  int rj[4]; float tj[4]; u32 cnt4[4]; u32 segb[4];
#pragma unroll
  for (int j = 0; j < 4; ++j) {
    rj[j] = r0 + (wr * 4 + j) * 16 + lm;
    tj[j] = tacc[rj[j]];
    cnt4[j] = 0;
    segb[j] = (u32)(rj[j] * NSEG + q * 8 + wc * 4 + lq) * SCAP;
  }
  // stage A tile for it=0 + column half-norms
  {
    const int c0 = q * 4096;
#pragma unroll
    for (int s = 0; s < 8; ++s) {
      int g = w * 8 + s;
      stage_group(X + (size_t)(c0 + (g & 7) * 16 + lm) * ND + (g >> 3) * 32 + koff,
                  &ldsA[g * 512], l);
    }
    if (t < 128) nchs[t] = 0.5f * norms[c0 + t];
  }
  __syncthreads();

  for (int it = 0; it < 32; ++it) {
    const int c0 = q * 4096 + it * 128;
    f32x4 acc[4][4];
#pragma unroll
    for (int i = 0; i < 4; ++i)
#pragma unroll
      for (int j = 0; j < 4; ++j) acc[i][j] = (f32x4){0.f, 0.f, 0.f, 0.f};

#pragma unroll
    for (int k = 0; k < 4; ++k) {
      bf16x8 af[4], bv[4];
#pragma unroll
      for (int i = 0; i < 4; ++i)
        af[i] = __builtin_bit_cast(bf16x8,
                 *(const ushort8*)(&ldsA[(k * 8 + wc * 4 + i) * 512 + l * 8]));
#pragma unroll
      for (int j = 0; j < 4; ++j)
        bv[j] = __builtin_bit_cast(bf16x8,
                 *(const ushort8*)(&ldsB[(k * 8 + wr * 4 + j) * 512 + l * 8]));
#pragma unroll
      for (int i = 0; i < 4; ++i)
#pragma unroll
        for (int j = 0; j < 4; ++j)
          acc[i][j] = __builtin_amdgcn_mfma_f32_16x16x32_bf16(af[i], bv[j], acc[i][j], 0, 0, 0);
    }

    f32x4 nch4[4];
#pragma unroll
    for (int i = 0; i < 4; ++i)
      nch4[i] = *(const f32x4*)(&nchs[wc * 64 + i * 16 + lq * 4]);

    const bool dg = (c0 == r0);
#pragma unroll
    for (int i = 0; i < 4; ++i) {
#pragma unroll
      for (int j = 0; j < 4; ++j) {
#pragma unroll
        for (int v = 0; v < 4; ++v) {
          float val = acc[i][j][v] - nch4[i][v];   // = x_c.x_r - n_c/2
          bool p = (val >= tj[j]);
          if (dg) p = p && ((c0 + wc * 64 + i * 16 + lq * 4 + v) != rj[j]);
          if (p) {
            u32 c = cnt4[j];
            if (c < SCAP) cands[segb[j] + c] = val;
            cnt4[j] = c + 1;   // keep counting past cap -> overflow detect
          }
        }
      }
    }
    __syncthreads();  // all waves done reading ldsA / nchs
    if (it + 1 < 32) {
      const int c1 = c0 + 128;
#pragma unroll
      for (int s = 0; s < 8; ++s) {
        int g = w * 8 + s;
        stage_group(X + (size_t)(c1 + (g & 7) * 16 + lm) * ND + (g >> 3) * 32 + koff,
                    &ldsA[g * 512], l);
      }
      if (t < 128) nchs[t] = 0.5f * norms[c1 + t];
    }
    __syncthreads();  // drain staging
  }
#pragma unroll
  for (int j = 0; j < 4; ++j)
    counts[rj[j] * NSEG + q * 8 + wc * 4 + lq] = cnt4[j];
}

// ---------------- K5: per-row exact 33rd smallest among candidates --------
__global__ void k_select(const u32* __restrict__ counts, const float* __restrict__ cands,
                         const float* __restrict__ norms, float* __restrict__ out) {
  int w = threadIdx.x >> 6, l = threadIdx.x & 63;
  int r = blockIdx.x * 4 + w;  // grid 4096
  u32 myc = (l < NSEG) ? counts[r * NSEG + l] : 0u;
  u32 tot = myc, mx = myc;
#pragma unroll
  for (int off = 1; off < 64; off <<= 1) {
    tot += __shfl_xor(tot, off, 64);
    u32 o = (u32)__shfl_xor((int)mx, off, 64);
    mx = mx > o ? mx : o;
  }
  if (tot < NTH || mx > SCAP) return;  // fallback kernel owns this row

  const float* base = cands + (size_t)r * (NSEG * SCAP);
  float v0, v1, v2, v3, v4, v5;
#define LOADV(e, dst)                                        \
  {                                                          \
    int f = l + 64 * e;                                      \
    int sg = f / SCAP, sl = f - sg * SCAP;                   \
    u32 c = (u32)__shfl((int)myc, sg, 64);                   \
    float x = base[f];                                       \
    dst = (sl < (int)c) ? x : NEGF;                          \
  }
  LOADV(0, v0) LOADV(1, v1) LOADV(2, v2) LOADV(3, v3) LOADV(4, v4) LOADV(5, v5)
#undef LOADV

  float last = NEGF;
  for (int e = 0; e < NTH; ++e) {  // bigger val = closer; extract-max x33
    float m = fmaxf(fmaxf(fmaxf(v0, v1), fmaxf(v2, v3)), fmaxf(v4, v5));
#pragma unroll
    for (int off = 1; off < 64; off <<= 1) m = fmaxf(m, __shfl_xor(m, off, 64));
    bool mine = (v0 == m) || (v1 == m) || (v2 == m) || (v3 == m) || (v4 == m) || (v5 == m);
    unsigned long long bal = __ballot(mine);
    int owner = __ffsll(bal) - 1;
    if (l == owner) {
      if      (v0 == m) v0 = NEGF;
      else if (v1 == m) v1 = NEGF;
      else if (v2 == m) v2 = NEGF;
      else if (v3 == m) v3 = NEGF;
      else if (v4 == m) v4 = NEGF;
      else              v5 = NEGF;
    }
    last = m;
  }
  out[r] = sqrtf(fmaxf(norms[r] - 2.f * last, 0.f));  // sq = n_r - 2*val
}

// ---------------- K6: exact brute-force fallback (expected ~0 rows) -------
__global__ void k_fallback(const u32* __restrict__ counts, const u16* __restrict__ X,
                           const float* __restrict__ norms, float* __restrict__ out) {
  __shared__ float sq[NB];     // 64 KB
  __shared__ float xr[ND];
  __shared__ float rmin[256];
  __shared__ int   ridx[256];
  int t = threadIdx.x;
  for (int r = blockIdx.x; r < NB; r += 64) {  // grid 64
    u32 tot = 0, mx = 0;
    for (int s = 0; s < NSEG; ++s) {  // uniform scalar loads
      u32 c = counts[r * NSEG + s];
      tot += c; mx = c > mx ? c : mx;
    }
    if (tot >= NTH && mx <= SCAP) continue;  // uniform branch
    if (t < 128) xr[t] = bf2f(X[(size_t)r * ND + t]);
    __syncthreads();
    float n_r = norms[r];
    for (int jj = 0; jj < 64; ++jj) {
      int j = t + 256 * jj;
      const u16* xj = X + (size_t)j * ND;
      float dot = 0.f;
#pragma unroll
      for (int c8 = 0; c8 < 16; ++c8) {
        ushort8 vv = *(const ushort8*)(xj + c8 * 8);
#pragma unroll
        for (int u = 0; u < 8; ++u) dot += bf2f(vv[u]) * xr[c8 * 8 + u];
      }
      sq[j] = (j == r) ? POSF : fmaxf(n_r + norms[j] - 2.f * dot, 0.f);
    }
    __syncthreads();
    float last = 0.f;
    for (int e = 0; e < NTH; ++e) {
      float lm = POSF; int li = -1;
      for (int jj = 0; jj < 64; ++jj) {
        int j = t + 256 * jj;
        float s = sq[j];
        if (s < lm) { lm = s; li = j; }
      }
      rmin[t] = lm; ridx[t] = li;
      __syncthreads();
      if (t == 0) {
        float gm = POSF; int gi = -1;
        for (int u = 0; u < 256; ++u)
          if (rmin[u] < gm) { gm = rmin[u]; gi = ridx[u]; }
        sq[gi] = POSF;
        rmin[0] = gm;
      }
      __syncthreads();
      last = rmin[0];
      __syncthreads();
    }
    if (t == 0) out[r] = sqrtf(fmaxf(last, 0.f));
    __syncthreads();
  }
}

extern "C" void kernel_launch(void* const* d_in, const int* in_sizes, int n_in,
                              void* d_out, int out_size, void* d_ws, size_t ws_size,
                              hipStream_t stream) {
  const float* x = (const float*)d_in[0];
  float* out = (float*)d_out;
  char* ws = (char*)d_ws;
  u16*   X     = (u16*)  (ws + OFF_X);
  float* norms = (float*)(ws + OFF_NORM);
  float* tacc  = (float*)(ws + OFF_TACC);
  float* xbar  = (float*)(ws + OFF_XBAR);
  float* scal  = (float*)(ws + OFF_SCAL);
  u32*   cnts  = (u32*)  (ws + OFF_CNTS);
  float* cands = (float*)(ws + OFF_CAND);

  k_prep    <<<4096, 256, 0, stream>>>(x, X, norms, xbar, scal);
  k_stats   <<<64,   256, 0, stream>>>(X, norms, xbar, scal);
  k_thresh  <<<64,   256, 0, stream>>>(X, norms, xbar, scal, tacc);
  k_gram    <<<512,  256, 0, stream>>>(X, norms, tacc, cnts, cands);
  k_select  <<<4096, 256, 0, stream>>>(cnts, cands, norms, out);
  k_fallback<<<64,   256, 0, stream>>>(cnts, X, norms, out);
}

// Round 5
// 200.199 us; speedup vs baseline: 3.0791x; 1.5794x over previous
//
#include <hip/hip_runtime.h>

// k-th NN distance (k=32 -> 33rd smallest, self excluded), B=16384, D=128.
// R4 resubmit (container infra failure, no signal): k_gram restructured —
// double-buffered LDS A with issue-early staging (latency hidden under
// compute, single barrier/iter), B fragments in registers (no ldsB),
// XCD-aware block swizzle for L2 locality. k_fallback count-scan
// parallelized (one row/thread, vectorized).

typedef unsigned short u16;
typedef unsigned int   u32;
typedef __attribute__((ext_vector_type(8))) u16    ushort8;
typedef __attribute__((ext_vector_type(8))) __bf16 bf16x8;
typedef __attribute__((ext_vector_type(4))) float  f32x4;
typedef __attribute__((ext_vector_type(4))) u32    u32x4;

#define NB   16384
#define ND   128
#define NSEG 32           // segments per row = 4 q * 2 wc * 4 lq
#define SCAP 12           // slots per segment (mean ~2.25, 12 = ~6 sigma)
#define NTH  33           // 33rd smallest
#define ZWH  (-2.62f)     // WH quantile z: p~0.0044 -> ~72 cands/row
#define NEGF (-3.0e38f)
#define POSF ( 3.0e38f)

// ---- workspace layout (bytes), total ~31.6 MB ----
#define OFF_X    ((size_t)0)
#define OFF_NORM (OFF_X    + (size_t)NB * ND * 2)
#define OFF_TACC (OFF_NORM + (size_t)NB * 4)
#define OFF_XBAR (OFF_TACC + (size_t)NB * 4)
#define OFF_SCAL (OFF_XBAR + 512)
#define OFF_CNTS (OFF_SCAL + 256)
#define OFF_CAND (OFF_CNTS + (size_t)NB * NSEG * 4)

static __device__ __forceinline__ u16 f2bf(float f) {
  u32 u = __float_as_uint(f);
  u32 r = u + 0x7FFFu + ((u >> 16) & 1u);
  return (u16)(r >> 16);
}
static __device__ __forceinline__ float bf2f(u16 h) {
  return __uint_as_float(((u32)h) << 16);
}

#if defined(__has_builtin)
#if __has_builtin(__builtin_amdgcn_global_load_lds)
#define HAVE_GLDS 1
#endif
#endif

// Stage 16B/lane: LDS dest = wave-uniform base + lane*16 (linear).
static __device__ __forceinline__ void stage16(const u16* gsrc_lane,
                                               u16* lds_base, int l) {
#ifdef HAVE_GLDS
  __builtin_amdgcn_global_load_lds(
      (const __attribute__((address_space(1))) void*)gsrc_lane,
      (__attribute__((address_space(3))) void*)lds_base, 16, 0, 0);
#else
  *(ushort8*)(lds_base + l * 8) = *(const ushort8*)gsrc_lane;
#endif
}
// Stage 4B/lane (for the column-norm vector).
static __device__ __forceinline__ void stage4(const float* gsrc_lane,
                                              float* lds_base, int l) {
#ifdef HAVE_GLDS
  __builtin_amdgcn_global_load_lds(
      (const __attribute__((address_space(1))) void*)gsrc_lane,
      (__attribute__((address_space(3))) void*)lds_base, 4, 0, 0);
#else
  lds_base[l] = *gsrc_lane;
#endif
}

// ---------------- K1: bf16 convert + norms (+ zero stat accumulators) ----
__global__ void k_prep(const float* __restrict__ x, u16* __restrict__ X,
                       float* __restrict__ norms, float* xbar, float* scal) {
  if (blockIdx.x == 0) {
    int tt = threadIdx.x;
    if (tt < 128) xbar[tt] = 0.f;
    if (tt < 2)   scal[tt] = 0.f;
  }
  int w = threadIdx.x >> 6, l = threadIdx.x & 63;
  int r = blockIdx.x * 4 + w;  // grid 4096
  const float2* xr2 = (const float2*)(x + (size_t)r * ND);
  float2 a = xr2[l];
  u16 h0 = f2bf(a.x), h1 = f2bf(a.y);
  float b0 = bf2f(h0), b1 = bf2f(h1);
  float n = b0 * b0 + b1 * b1;
#pragma unroll
  for (int off = 1; off < 64; off <<= 1) n += __shfl_xor(n, off, 64);
  *(u32*)(X + (size_t)r * ND + 2 * l) = (u32)h0 | ((u32)h1 << 16);
  if (l == 0) norms[r] = n;
}

// ---------------- K2: column sums (x-bar) + sum(n), sum(n^2) -------------
__global__ void k_stats(const u16* __restrict__ X, const float* __restrict__ norms,
                        float* xbar, float* scal) {
  __shared__ float xs[2][128];
  __shared__ float red1[256], red2[256];
  int t = threadIdx.x, col = t & 127, half = t >> 7;
  int rbase = blockIdx.x * 256 + half * 128;  // grid 64
  float acc = 0.f;
  for (int rr = 0; rr < 128; ++rr)
    acc += bf2f(X[(size_t)(rbase + rr) * ND + col]);
  xs[half][col] = acc;
  float ln = norms[blockIdx.x * 256 + t];
  red1[t] = ln; red2[t] = ln * ln;
  __syncthreads();
  for (int s = 128; s > 0; s >>= 1) {
    if (t < s) { red1[t] += red1[t + s]; red2[t] += red2[t + s]; }
    __syncthreads();
  }
  if (t == 0) { atomicAdd(&scal[0], red1[0]); atomicAdd(&scal[1], red2[0]); }
  if (t < 128) atomicAdd(&xbar[t], xs[0][t] + xs[1][t]);
}

// ---------------- K3: per-row threshold via Wilson-Hilferty chi^2 --------
__global__ void k_thresh(const u16* __restrict__ X, const float* __restrict__ norms,
                         const float* __restrict__ xbar, const float* __restrict__ scal,
                         float* __restrict__ tacc) {
  __shared__ float xb[128];
  int t = threadIdx.x;
  if (t < 128) xb[t] = xbar[t] * (1.0f / NB);
  __syncthreads();
  int r = blockIdx.x * 256 + t;  // grid 64
  float n = norms[r];
  const u16* xr = X + (size_t)r * ND;
  float dot = 0.f;
#pragma unroll
  for (int c8 = 0; c8 < 16; ++c8) {
    ushort8 v = *(const ushort8*)(xr + c8 * 8);
#pragma unroll
    for (int j = 0; j < 8; ++j) dot += bf2f(v[j]) * xb[c8 * 8 + j];
  }
  float nbar = scal[0] * (1.0f / NB);
  float Vn = fmaxf(scal[1] * (1.0f / NB) - nbar * nbar, 0.f);
  float m = n + nbar - 2.f * dot;             // exact E_j[sq_rj]
  float v = Vn + 4.f * n * (nbar / ND);       // Var_j[sq_rj] model
  float nu = 2.f * m * m / v;
  float cc = v / (2.f * m);
  float a1 = 2.f / (9.f * nu);
  float inner = 1.f - a1 + ZWH * sqrtf(a1);
  float tsq = cc * nu * inner * inner * inner;
  tacc[r] = 0.5f * (n - tsq);   // val = acc - nc/2 >= tacc  <=>  sq <= tsq
}

// ---------------- K4: MFMA gram + fused filter into private segments -----
// 512 blocks, XCD-swizzled q-major: per-XCD working set = 1MB A-quarter +
// 2MB B-rows < 4MB L2. 4 waves as 2x2 of 64x64. B frags in registers.
// Double-buffered ldsA: stage(it+1) issued BEFORE compute(it); the
// compiler's vmcnt(0)+barrier at the single __syncthreads() drains it
// ~a full compute phase after issue -> latency hidden.
#define FILTER_TILE(DGC)                                                      \
  _Pragma("unroll") for (int i = 0; i < 4; ++i) {                             \
    _Pragma("unroll") for (int j = 0; j < 4; ++j) {                           \
      _Pragma("unroll") for (int v = 0; v < 4; ++v) {                         \
        float val = acc[i][j][v] - nch4[i][v];                                \
        bool p = (val >= tj[j]);                                              \
        if (DGC) p = p && ((c0 + wc * 64 + i * 16 + lq * 4 + v) != rj[j]);    \
        if (p) {                                                              \
          u32 c = cnt4[j];                                                    \
          if (c < SCAP) cands[segb[j] + c] = val;                             \
          cnt4[j] = c + 1;                                                    \
        }                                                                     \
      }                                                                       \
    }                                                                         \
  }

__global__ __launch_bounds__(256, 2) void k_gram(
    const u16* __restrict__ X, const float* __restrict__ norms,
    const float* __restrict__ tacc, u32* __restrict__ counts,
    float* __restrict__ cands) {
  __shared__ u16 ldsA[2][32 * 512];            // 2 x 32KB
  __shared__ __align__(16) float nchs[2][128];
  const int bid = blockIdx.x;
  const int logical = (bid & 7) * 64 + (bid >> 3);   // XCD-chunked, bijective
  const int q = logical >> 7, strip = logical & 127;
  const int r0 = strip * 128;
  const int t = threadIdx.x, w = t >> 6, l = t & 63;
  const int wr = w & 1, wc = w >> 1;
  const int lm = l & 15, lq = l >> 4;
  const int koff = lq * 8;

  // B fragments (owned rows) -> registers, loaded once. Same fragment
  // mapping as the verified LDS path: lane l holds row (.. +lm), k-chunk lq*8.
  bf16x8 bfrag[4][4];  // [k][j]
#pragma unroll
  for (int k = 0; k < 4; ++k)
#pragma unroll
    for (int j = 0; j < 4; ++j)
      bfrag[k][j] = __builtin_bit_cast(bf16x8, *(const ushort8*)(
          X + (size_t)(r0 + (wr * 4 + j) * 16 + lm) * ND + k * 32 + koff));

  int rj[4]; float tj[4]; u32 cnt4[4]; u32 segb[4];
#pragma unroll
  for (int j = 0; j < 4; ++j) {
    rj[j] = r0 + (wr * 4 + j) * 16 + lm;
    tj[j] = tacc[rj[j]];
    cnt4[j] = 0;
    segb[j] = (u32)(rj[j] * NSEG + q * 8 + wc * 4 + lq) * SCAP;
  }

  // prologue: stage tile 0 into buffer 0
  {
    const int c0 = q * 4096;
#pragma unroll
    for (int s = 0; s < 8; ++s) {
      int g = w * 8 + s;
      stage16(X + (size_t)(c0 + (g & 7) * 16 + lm) * ND + (g >> 3) * 32 + koff,
              &ldsA[0][g * 512], l);
    }
    if (w < 2) stage4(norms + c0 + w * 64 + l, &nchs[0][w * 64], l);
  }
  __syncthreads();

  for (int it = 0; it < 32; ++it) {
    const int cur = it & 1;
    const int c0 = q * 4096 + it * 128;
    // issue next-tile staging FIRST (into the other buffer)
    if (it + 1 < 32) {
      const int c1 = c0 + 128;
      u16* dstA = ldsA[cur ^ 1];
#pragma unroll
      for (int s = 0; s < 8; ++s) {
        int g = w * 8 + s;
        stage16(X + (size_t)(c1 + (g & 7) * 16 + lm) * ND + (g >> 3) * 32 + koff,
                &dstA[g * 512], l);
      }
      if (w < 2) stage4(norms + c1 + w * 64 + l, &nchs[cur ^ 1][w * 64], l);
    }
    __builtin_amdgcn_sched_barrier(0);  // pin staging issue before compute

    f32x4 acc[4][4];
#pragma unroll
    for (int i = 0; i < 4; ++i)
#pragma unroll
      for (int j = 0; j < 4; ++j) acc[i][j] = (f32x4){0.f, 0.f, 0.f, 0.f};

    const u16* srcA = ldsA[cur];
#pragma unroll
    for (int k = 0; k < 4; ++k) {
      bf16x8 af[4];
#pragma unroll
      for (int i = 0; i < 4; ++i)
        af[i] = __builtin_bit_cast(bf16x8,
                 *(const ushort8*)(&srcA[(k * 8 + wc * 4 + i) * 512 + l * 8]));
#pragma unroll
      for (int i = 0; i < 4; ++i)
#pragma unroll
        for (int j = 0; j < 4; ++j)
          acc[i][j] = __builtin_amdgcn_mfma_f32_16x16x32_bf16(af[i], bfrag[k][j], acc[i][j], 0, 0, 0);
    }

    f32x4 nch4[4];
#pragma unroll
    for (int i = 0; i < 4; ++i) {
      nch4[i] = *(const f32x4*)(&nchs[cur][wc * 64 + i * 16 + lq * 4]);
      nch4[i] = nch4[i] * 0.5f;
    }

    if (c0 == r0) { FILTER_TILE(true) } else { FILTER_TILE(false) }

    __syncthreads();  // drains vmcnt(0): next tile staged + stores retired
  }
#pragma unroll
  for (int j = 0; j < 4; ++j)
    counts[rj[j] * NSEG + q * 8 + wc * 4 + lq] = cnt4[j];
}

// ---------------- K5: per-row exact 33rd smallest among candidates --------
__global__ void k_select(const u32* __restrict__ counts, const float* __restrict__ cands,
                         const float* __restrict__ norms, float* __restrict__ out) {
  int w = threadIdx.x >> 6, l = threadIdx.x & 63;
  int r = blockIdx.x * 4 + w;  // grid 4096
  u32 myc = (l < NSEG) ? counts[r * NSEG + l] : 0u;
  u32 tot = myc, mx = myc;
#pragma unroll
  for (int off = 1; off < 64; off <<= 1) {
    tot += __shfl_xor(tot, off, 64);
    u32 o = (u32)__shfl_xor((int)mx, off, 64);
    mx = mx > o ? mx : o;
  }
  if (tot < NTH || mx > SCAP) return;  // fallback kernel owns this row

  const float* base = cands + (size_t)r * (NSEG * SCAP);
  float v0, v1, v2, v3, v4, v5;
#define LOADV(e, dst)                                        \
  {                                                          \
    int f = l + 64 * e;                                      \
    int sg = f / SCAP, sl = f - sg * SCAP;                   \
    u32 c = (u32)__shfl((int)myc, sg, 64);                   \
    float x = base[f];                                       \
    dst = (sl < (int)c) ? x : NEGF;                          \
  }
  LOADV(0, v0) LOADV(1, v1) LOADV(2, v2) LOADV(3, v3) LOADV(4, v4) LOADV(5, v5)
#undef LOADV

  float last = NEGF;
  for (int e = 0; e < NTH; ++e) {  // bigger val = closer; extract-max x33
    float m = fmaxf(fmaxf(fmaxf(v0, v1), fmaxf(v2, v3)), fmaxf(v4, v5));
#pragma unroll
    for (int off = 1; off < 64; off <<= 1) m = fmaxf(m, __shfl_xor(m, off, 64));
    bool mine = (v0 == m) || (v1 == m) || (v2 == m) || (v3 == m) || (v4 == m) || (v5 == m);
    unsigned long long bal = __ballot(mine);
    int owner = __ffsll(bal) - 1;
    if (l == owner) {
      if      (v0 == m) v0 = NEGF;
      else if (v1 == m) v1 = NEGF;
      else if (v2 == m) v2 = NEGF;
      else if (v3 == m) v3 = NEGF;
      else if (v4 == m) v4 = NEGF;
      else              v5 = NEGF;
    }
    last = m;
  }
  out[r] = sqrtf(fmaxf(norms[r] - 2.f * last, 0.f));  // sq = n_r - 2*val
}

// ---------------- K6: exact brute-force fallback (expected ~0 rows) -------
// Phase 1: one row/thread, vectorized count scan -> LDS bad-list.
// Phase 2: whole-block brute force per bad row (rare).
__global__ void k_fallback(const u32* __restrict__ counts, const u16* __restrict__ X,
                           const float* __restrict__ norms, float* __restrict__ out) {
  __shared__ float sq[NB];     // 64 KB
  __shared__ float xr[ND];
  __shared__ float rmin[256];
  __shared__ int   ridx[256];
  __shared__ int   nbad;
  __shared__ int   badlist[256];
  int t = threadIdx.x;
  if (t == 0) nbad = 0;
  __syncthreads();
  int r = blockIdx.x * 256 + t;   // grid 64: covers NB exactly
  u32 tot = 0, mx = 0;
#pragma unroll
  for (int s4 = 0; s4 < 8; ++s4) {
    u32x4 c = *(const u32x4*)(counts + (size_t)r * NSEG + s4 * 4);
#pragma unroll
    for (int u = 0; u < 4; ++u) { tot += c[u]; mx = c[u] > mx ? c[u] : mx; }
  }
  if (tot < NTH || mx > SCAP) { int p = atomicAdd(&nbad, 1); badlist[p] = r; }
  __syncthreads();
  int nb = nbad;
  for (int ii = 0; ii < nb; ++ii) {
    int rr = badlist[ii];
    if (t < 128) xr[t] = bf2f(X[(size_t)rr * ND + t]);
    __syncthreads();
    float n_r = norms[rr];
    for (int jj = 0; jj < 64; ++jj) {
      int j = t + 256 * jj;
      const u16* xj = X + (size_t)j * ND;
      float dot = 0.f;
#pragma unroll
      for (int c8 = 0; c8 < 16; ++c8) {
        ushort8 vv = *(const ushort8*)(xj + c8 * 8);
#pragma unroll
        for (int u = 0; u < 8; ++u) dot += bf2f(vv[u]) * xr[c8 * 8 + u];
      }
      sq[j] = (j == rr) ? POSF : fmaxf(n_r + norms[j] - 2.f * dot, 0.f);
    }
    __syncthreads();
    float last = 0.f;
    for (int e = 0; e < NTH; ++e) {
      float lm = POSF; int li = -1;
      for (int jj = 0; jj < 64; ++jj) {
        int j = t + 256 * jj;
        float s = sq[j];
        if (s < lm) { lm = s; li = j; }
      }
      rmin[t] = lm; ridx[t] = li;
      __syncthreads();
      if (t == 0) {
        float gm = POSF; int gi = -1;
        for (int u = 0; u < 256; ++u)
          if (rmin[u] < gm) { gm = rmin[u]; gi = ridx[u]; }
        sq[gi] = POSF;
        rmin[0] = gm;
      }
      __syncthreads();
      last = rmin[0];
      __syncthreads();
    }
    if (t == 0) out[rr] = sqrtf(fmaxf(last, 0.f));
    __syncthreads();
  }
}

extern "C" void kernel_launch(void* const* d_in, const int* in_sizes, int n_in,
                              void* d_out, int out_size, void* d_ws, size_t ws_size,
                              hipStream_t stream) {
  const float* x = (const float*)d_in[0];
  float* out = (float*)d_out;
  char* ws = (char*)d_ws;
  u16*   X     = (u16*)  (ws + OFF_X);
  float* norms = (float*)(ws + OFF_NORM);
  float* tacc  = (float*)(ws + OFF_TACC);
  float* xbar  = (float*)(ws + OFF_XBAR);
  float* scal  = (float*)(ws + OFF_SCAL);
  u32*   cnts  = (u32*)  (ws + OFF_CNTS);
  float* cands = (float*)(ws + OFF_CAND);

  k_prep    <<<4096, 256, 0, stream>>>(x, X, norms, xbar, scal);
  k_stats   <<<64,   256, 0, stream>>>(X, norms, xbar, scal);
  k_thresh  <<<64,   256, 0, stream>>>(X, norms, xbar, scal, tacc);
  k_gram    <<<512,  256, 0, stream>>>(X, norms, tacc, cnts, cands);
  k_select  <<<4096, 256, 0, stream>>>(cnts, cands, norms, out);
  k_fallback<<<64,   256, 0, stream>>>(cnts, X, norms, out);
}